// Round 1
// baseline (354.970 us; speedup 1.0000x reference)
//
#include <hip/hip_runtime.h>
#include <math.h>

#define EMB 1024
#define NB 4
#define SQ 2048
#define TOK (NB*SQ)   // 8192

typedef __attribute__((ext_vector_type(8))) short bhalf8;   // 8 bf16 (4 VGPRs)
typedef __attribute__((ext_vector_type(4))) float f32x4;

__device__ __forceinline__ unsigned short f32_to_bf16(float f) {
    unsigned int u = __float_as_uint(f);
    u += 0x7FFFu + ((u >> 16) & 1u);       // round-to-nearest-even
    return (unsigned short)(u >> 16);
}
__device__ __forceinline__ float bf16_to_f32(unsigned short h) {
    return __uint_as_float(((unsigned int)h) << 16);
}
__device__ __forceinline__ unsigned short f32_to_f16(float f) {
    union { _Float16 h; unsigned short u; } c; c.h = (_Float16)f; return c.u;
}
__device__ __forceinline__ float f16_to_f32(unsigned short u) {
    union { _Float16 h; unsigned short u; } c; c.u = u; return (float)c.h;
}

// ---------------- fused fp32 -> bf16 conversion: x (8192 blocks) + weights (5120) ----------------
__global__ __launch_bounds__(256) void convert_all_kernel(
    const float* __restrict__ x,  unsigned short* __restrict__ x_bf,
    const float* __restrict__ rot, const float* __restrict__ ent,
    const float* __restrict__ gw, unsigned short* __restrict__ w_bf) {
    const int EE4 = EMB * EMB / 4;
    const float* src;
    unsigned short* dst;
    float scale = 1.0f;
    int j;
    if (blockIdx.x < TOK*EMB/4/256) {
        src = x; dst = x_bf; j = blockIdx.x * 256 + threadIdx.x;
        float4 v = ((const float4*)src)[j];
        ushort4 o = { f32_to_bf16(v.x), f32_to_bf16(v.y), f32_to_bf16(v.z), f32_to_bf16(v.w) };
        ((ushort4*)dst)[j] = o;
        return;
    }
    const int i = (blockIdx.x - TOK*EMB/4/256) * 256 + threadIdx.x;   // over 5*EE4
    j = i; dst = w_bf;
    if (i < 3 * EE4) {
        src = rot;
        if (i < EE4) scale = 0.125f;                // 1/sqrt(64) folded into q-rows
    } else if (i < 4 * EE4) { src = ent; j = i - 3 * EE4; }
    else                    { src = gw;  j = i - 4 * EE4; }
    float4 v = ((const float4*)src)[j];
    ushort4 o;
    o.x = f32_to_bf16(v.x * scale);
    o.y = f32_to_bf16(v.y * scale);
    o.z = f32_to_bf16(v.z * scale);
    o.w = f32_to_bf16(v.w * scale);
    ((ushort4*)dst)[i] = o;
}

// ---------------- async global->LDS 16B staging helper ----------------
__device__ __forceinline__ void async_load16(const unsigned short* gp, unsigned short* lp) {
    __builtin_amdgcn_global_load_lds(
        (const __attribute__((address_space(1))) unsigned int*)gp,
        (__attribute__((address_space(3))) unsigned int*)lp,
        16, 0, 0);
}

// =====================================================================================
// 256x256-tile, BK=64, 8-wave (2Mx4N), 8-phase schedule with counted vmcnt (T2+T3+T4+T5).
// NT GEMM: C[m,n] = sum_k A[m,k]*B[n,k], bf16 in, fp32 acc.
// LDS: 2 dbuf x 256x64 per operand = 128 KiB (1 block/CU, 2 waves/SIMD).
// Swizzle: same verified XOR-colblock scheme as the 128^2 kernel (0 bank conflicts, R4).
// Per K-tile (4 phases): P1 computes (m0-1 x n0-3), reads ALL 8 B-frags + 4 A-frags (12
// ds_read_b128); P2/P3/P4 read 4 A-frags each (B held in regs). B-halves are therefore
// fully consumed at P1 -> their LDS slots are free for prefetch from P2 on.
// Stage stream (1 half-tile = 2 global_load_lds/thread per phase):
//   P1: A-hi(t+1) -> other buffer (fully safe)
//   P2: B-lo(t+2) -> this buffer (slot freed at end of P1)
//   P3: B-hi(t+2) -> this buffer (freed at end of P1)
//   P4: A-lo(t+2) -> this buffer (slot read this phase; reads are issued before the
//       stage and the load return latency >> ds_read pipe latency under phase-lockstep
//       barriers -- the m201-verified overlap)
// vmcnt(6) (= 3 half-tiles in flight) once per K-tile at P4 guarantees tile t+1 fully
// landed before its first ds_read. Requires nkt >= 2 (all calls have nkt in {16,32}).
// MODE 0: bf16 C; MODE 1: f16 C; MODE 2: Fout = sigmoid(acc) * bf16(Obf)
// =====================================================================================

#define BAR()  __builtin_amdgcn_s_barrier()
#define LGK0() do { asm volatile("s_waitcnt lgkmcnt(0)" ::: "memory"); \
                    __builtin_amdgcn_sched_barrier(0); } while (0)
#define VMC6() asm volatile("s_waitcnt vmcnt(6)" ::: "memory")
#define VMC0() asm volatile("s_waitcnt vmcnt(0)" ::: "memory")

#define STAGE_A(buf, half, kofs) do { \
    async_load16(aG0 + (half)*aH + (kofs), &As[buf][(half)*8192 +        w*512]); \
    async_load16(aG1 + (half)*aH + (kofs), &As[buf][(half)*8192 + 4096 + w*512]); \
} while (0)
#define STAGE_B(buf, half, kofs) do { \
    async_load16(bG0 + (half)*bH + (kofs), &Bs[buf][(half)*8192 +        w*512]); \
    async_load16(bG1 + (half)*bH + (kofs), &Bs[buf][(half)*8192 + 4096 + w*512]); \
} while (0)

#define READ_A(p) do { \
    af[0][0] = *(const bhalf8*)(aRd + ((p)*2    )*1024 + kqs0); \
    af[0][1] = *(const bhalf8*)(aRd + ((p)*2    )*1024 + kqs1); \
    af[1][0] = *(const bhalf8*)(aRd + ((p)*2 + 1)*1024 + kqs0); \
    af[1][1] = *(const bhalf8*)(aRd + ((p)*2 + 1)*1024 + kqs1); \
} while (0)

#define READ_B() do { \
    _Pragma("unroll") \
    for (int ni_ = 0; ni_ < 4; ++ni_) { \
        bfv[ni_][0] = *(const bhalf8*)(bRd + ni_*1024 + kqs0); \
        bfv[ni_][1] = *(const bhalf8*)(bRd + ni_*1024 + kqs1); \
    } \
} while (0)

#define MFMA16(p) do { \
    __builtin_amdgcn_s_setprio(1); \
    _Pragma("unroll") \
    for (int h_ = 0; h_ < 2; ++h_) { \
        _Pragma("unroll") \
        for (int mi_ = 0; mi_ < 2; ++mi_) { \
            _Pragma("unroll") \
            for (int ni_ = 0; ni_ < 4; ++ni_) \
                acc[(p)*2 + mi_][ni_] = __builtin_amdgcn_mfma_f32_16x16x32_bf16( \
                    af[mi_][h_], bfv[ni_][h_], acc[(p)*2 + mi_][ni_], 0, 0, 0); \
        } \
    } \
    __builtin_amdgcn_s_setprio(0); \
} while (0)

template <int MODE>
__global__ __launch_bounds__(512, 2) void gemm_nt_8p(
    const unsigned short* __restrict__ A,
    const unsigned short* __restrict__ B,
    void* __restrict__ C,
    const unsigned short* __restrict__ Obf,
    float* __restrict__ Fout,
    int M, int N, int K, int lda, int ldb, int ldc,
    long sA, long sB, long sC)
{
    __shared__ __align__(16) unsigned short As[2][16384];   // 64 KB  [buf][256*64]
    __shared__ __align__(16) unsigned short Bs[2][16384];   // 64 KB

    const int bz = blockIdx.z;
    const unsigned short* Ab = A + (long)bz * sA;
    const unsigned short* Bb = B + (long)bz * sB;
    const int bm = blockIdx.x * 256;
    const int bn = blockIdx.y * 256;
    const int t = threadIdx.x;
    const int w = t >> 6;        // wave 0..7
    const int l = t & 63;        // lane

    // staging lane geometry: wave-instr covers 8 rows x 64 halves (1 KB);
    // lane l -> (row = +l>>3, physical colblock l&7) holding logical cb = (l&7)^(l>>3)
    const int srow = l >> 3;
    const int scol = (((l & 7) ^ (l >> 3)) * 8);

    // fragment read offsets (same verified math as 128^2 kernel: row&7 == l&7)
    const int fr = l & 15;
    const int kqs0 = ((((l >> 4)    ) ^ (l & 7)) * 8);
    const int kqs1 = (((4 + (l >> 4)) ^ (l & 7)) * 8);

    const int wm = (w >> 2) * 128;   // WARPS_M = 2
    const int wn = (w & 3) * 64;     // WARPS_N = 4

    f32x4 acc[8][4];
    f32x4 zero = {0.f, 0.f, 0.f, 0.f};
    #pragma unroll
    for (int i = 0; i < 8; ++i)
        #pragma unroll
        for (int j = 0; j < 4; ++j) acc[i][j] = zero;

    // per-thread global stage bases (instr r covers rows (r*8+w)*8 + srow)
    const unsigned short* aG0 = Ab + (long)(bm + (    w)*8 + srow) * lda + scol;
    const unsigned short* aG1 = Ab + (long)(bm + (8 + w)*8 + srow) * lda + scol;
    const unsigned short* bG0 = Bb + (long)(bn + (    w)*8 + srow) * ldb + scol;
    const unsigned short* bG1 = Bb + (long)(bn + (8 + w)*8 + srow) * ldb + scol;
    const long aH = (long)128 * lda;   // A half-tile row offset
    const long bH = (long)128 * ldb;

    const int nkt = K >> 6;            // >= 2 required (16 or 32 here)

    // ---- prologue: tile0 complete + tile1 {B-lo, B-hi, A-lo} ----
    STAGE_A(0, 0, 0);  STAGE_A(0, 1, 0);
    STAGE_B(0, 0, 0);  STAGE_B(0, 1, 0);
    STAGE_B(1, 0, 64); STAGE_B(1, 1, 64);
    STAGE_A(1, 0, 64);
    VMC6();                            // tile0's 8 loads landed; tile1's 6 in flight
    BAR();

    for (int kt = 0; kt < nkt; ++kt) {
        const int cur = kt & 1, nxt = cur ^ 1;
        const unsigned short* aRd = &As[cur][(wm + fr) * 64];
        const unsigned short* bRd = &Bs[cur][(wn + fr) * 64];
        const bool s1 = (kt + 1 < nkt);
        const bool s2 = (kt + 2 < nkt);
        const int k1 = (kt + 1) << 6;
        const int k2 = (kt + 2) << 6;

        bhalf8 bfv[4][2], af[2][2];

        // ---- P1: all B frags + A m0-1; prefetch A-hi(kt+1) into other buffer ----
        READ_B();
        READ_A(0);
        if (s1) STAGE_A(nxt, 1, k1);
        BAR(); LGK0();
        MFMA16(0);
        BAR();

        // ---- P2: A m2-3; prefetch B-lo(kt+2) (slot freed at end of P1) ----
        READ_A(1);
        if (s2) STAGE_B(cur, 0, k2);
        BAR(); LGK0();
        MFMA16(1);
        BAR();

        // ---- P3: A m4-5; prefetch B-hi(kt+2) ----
        READ_A(2);
        if (s2) STAGE_B(cur, 1, k2);
        BAR(); LGK0();
        MFMA16(2);
        BAR();

        // ---- P4: A m6-7; prefetch A-lo(kt+2); counted vmcnt once per K-tile ----
        READ_A(3);
        if (s2) { STAGE_A(cur, 0, k2); VMC6(); }
        else    { VMC0(); }
        BAR(); LGK0();
        MFMA16(3);
        BAR();
    }

    // C/D layout (m89-verified): col = lane&15, row = (lane>>4)*4 + reg
    const int crow = (l >> 4) * 4;
    const int ccol = l & 15;
    #pragma unroll
    for (int mi = 0; mi < 8; ++mi) {
        #pragma unroll
        for (int ni = 0; ni < 4; ++ni) {
            #pragma unroll
            for (int r = 0; r < 4; ++r) {
                const int gr = bm + wm + mi*16 + crow + r;
                const int gc = bn + wn + ni*16 + ccol;
                const float v = acc[mi][ni][r];
                const long idx = (long)gr * ldc + gc;
                if (MODE == 0) {
                    ((unsigned short*)C)[(long)bz*sC + idx] = f32_to_bf16(v);
                } else if (MODE == 1) {
                    ((unsigned short*)C)[(long)bz*sC + idx] = f32_to_f16(v);
                } else {
                    const float o = bf16_to_f32(Obf[idx]);
                    const float g = 1.0f / (1.0f + __expf(-v));
                    Fout[idx] = g * o;
                }
            }
        }
    }
}

#undef BAR
#undef LGK0
#undef VMC6
#undef VMC0
#undef STAGE_A
#undef STAGE_B
#undef READ_A
#undef READ_B
#undef MFMA16

// ---------------- row softmax: f16 scores in, bf16 attn out (row len 2048) ----------------
__global__ __launch_bounds__(256) void softmax_kernel(const unsigned short* __restrict__ sc,
                                                      unsigned short* __restrict__ attn) {
    const long row = blockIdx.x;
    const unsigned short* p = sc + row * SQ;
    unsigned short* q = attn + row * SQ;
    const int t = threadIdx.x;
    const int w = t >> 6, l = t & 63;
    union { bhalf8 v; unsigned short u[8]; } in;
    in.v = ((const bhalf8*)p)[t];
    float f[8];
    float m = -1e30f;
    #pragma unroll
    for (int j = 0; j < 8; ++j) { f[j] = f16_to_f32(in.u[j]); m = fmaxf(m, f[j]); }
    #pragma unroll
    for (int off = 32; off; off >>= 1) m = fmaxf(m, __shfl_xor(m, off));
    __shared__ float smax[4], ssum[4];
    if (l == 0) smax[w] = m;
    __syncthreads();
    m = fmaxf(fmaxf(smax[0], smax[1]), fmaxf(smax[2], smax[3]));
    float s = 0.f;
    #pragma unroll
    for (int j = 0; j < 8; ++j) { f[j] = __expf(f[j] - m); s += f[j]; }
    #pragma unroll
    for (int off = 32; off; off >>= 1) s += __shfl_xor(s, off);
    if (l == 0) ssum[w] = s;
    __syncthreads();
    const float inv = 1.0f / (ssum[0] + ssum[1] + ssum[2] + ssum[3]);
    union { bhalf8 v; unsigned short u[8]; } o;
    #pragma unroll
    for (int j = 0; j < 8; ++j) o.u[j] = f32_to_bf16(f[j] * inv);
    ((bhalf8*)q)[t] = o.v;
}

// ---------------- transpose v (per batch: (2048 x 1024, ld 3072) -> (1024 x 2048)) ----------------
__global__ void transpose_v(const unsigned short* __restrict__ qkv,
                            unsigned short* __restrict__ vT) {
    __shared__ unsigned short tile[32][33];
    const int b = blockIdx.z;
    const unsigned short* v = qkv + (long)b * SQ * (3*EMB) + 2*EMB;
    const int e = blockIdx.x * 32 + threadIdx.x;
    const int s = blockIdx.y * 32 + threadIdx.y;
    tile[threadIdx.y][threadIdx.x] = v[(long)s * (3*EMB) + e];
    __syncthreads();
    const int so = blockIdx.y * 32 + threadIdx.x;
    const int eo = blockIdx.x * 32 + threadIdx.y;
    vT[(long)b * EMB * SQ + (long)eo * SQ + so] = tile[threadIdx.x][threadIdx.y];
}

extern "C" void kernel_launch(void* const* d_in, const int* in_sizes, int n_in,
                              void* d_out, int out_size, void* d_ws, size_t ws_size,
                              hipStream_t stream) {
    const float* rot = (const float*)d_in[0];   // (3E, E) row-major
    const float* ent = (const float*)d_in[1];   // (E, E)
    const float* x   = (const float*)d_in[2];   // (B, S, E)
    const float* gw  = (const float*)d_in[3];   // (E, E)
    float* outp = (float*)d_out;
    char* ws = (char*)d_ws;

    size_t off = 0;
    unsigned short* x_bf    = (unsigned short*)(ws + off); off += (size_t)TOK*EMB*2;     // 16 MB
    unsigned short* wqkv_bf = (unsigned short*)(ws + off); off += (size_t)3*EMB*EMB*2;   // 6 MB
    unsigned short* wout_bf = (unsigned short*)(ws + off); off += (size_t)EMB*EMB*2;     // 2 MB
    unsigned short* gate_bf = (unsigned short*)(ws + off); off += (size_t)EMB*EMB*2;     // 2 MB
    unsigned short* qkv_bf  = (unsigned short*)(ws + off); off += (size_t)TOK*3*EMB*2;   // 48 MB
    unsigned short* vT_bf   = (unsigned short*)(ws + off); off += (size_t)NB*EMB*SQ*2;   // 16 MB
    unsigned short* sc_f16  = (unsigned short*)(ws + off); off += (size_t)NB*SQ*SQ*2;    // 32 MB
    // Aliases (lifetimes disjoint, all launches sequential on one stream):
    unsigned short* attn_bf = qkv_bf;                        // qkv dead after K2; attn live K3->K4
    unsigned short* ao_bf   = x_bf;                          // x dead after K1; ao live K4->K5
    unsigned short* out_bf  = qkv_bf + (size_t)NB*SQ*SQ;     // qkv[32MB:48MB], live K5->K6

    // K0: all converts in one launch
    convert_all_kernel<<<dim3(TOK*EMB/4/256 + 5*EMB*EMB/4/256), dim3(256), 0, stream>>>(
        x, x_bf, rot, ent, gw, wqkv_bf);

    // K1: qkv = x @ w_qkv^T   (8192 x 3072, K=1024) -> bf16   [384 blocks]
    gemm_nt_8p<0><<<dim3(TOK/256, 3*EMB/256, 1), dim3(512), 0, stream>>>(
        x_bf, wqkv_bf, qkv_bf, nullptr, nullptr,
        TOK, 3*EMB, EMB, EMB, EMB, 3*EMB, 0, 0, 0);

    // transpose v -> vT (per batch E x S)
    transpose_v<<<dim3(EMB/32, SQ/32, NB), dim3(32, 32), 0, stream>>>(qkv_bf, vT_bf);

    // K2: scores = q @ k^T per batch (2048 x 2048, K=1024) -> f16   [256 blocks, exact fill]
    gemm_nt_8p<1><<<dim3(SQ/256, SQ/256, NB), dim3(512), 0, stream>>>(
        qkv_bf, qkv_bf + EMB, sc_f16, nullptr, nullptr,
        SQ, SQ, EMB, 3*EMB, 3*EMB, SQ,
        (long)SQ*3*EMB, (long)SQ*3*EMB, (long)SQ*SQ);

    // K3: softmax rows (f16 in, bf16 out)
    softmax_kernel<<<dim3(NB*SQ), dim3(256), 0, stream>>>(sc_f16, attn_bf);

    // K4: attn_out = attn @ v per batch (2048 x 1024, K=2048); B = vT (NT form)  [128 blocks]
    gemm_nt_8p<0><<<dim3(SQ/256, EMB/256, NB), dim3(512), 0, stream>>>(
        attn_bf, vT_bf, ao_bf, nullptr, nullptr,
        SQ, EMB, SQ, SQ, SQ, EMB,
        (long)SQ*SQ, (long)EMB*SQ, (long)SQ*EMB);

    // K5: out = attn_out @ w_out^T (8192 x 1024, K=1024) -> bf16   [128 blocks]
    gemm_nt_8p<0><<<dim3(TOK/256, EMB/256, 1), dim3(512), 0, stream>>>(
        ao_bf, wout_bf, out_bf, nullptr, nullptr,
        TOK, EMB, EMB, EMB, EMB, EMB, 0, 0, 0);

    // K6: result = sigmoid(out @ gate_w^T) * out_bf -> fp32 d_out   [128 blocks]
    gemm_nt_8p<2><<<dim3(TOK/256, EMB/256, 1), dim3(512), 0, stream>>>(
        out_bf, gate_bf, nullptr, out_bf, outp,
        TOK, EMB, EMB, EMB, EMB, EMB, 0, 0, 0);
}

// Round 2
// 329.550 us; speedup vs baseline: 1.0771x; 1.0771x over previous
//
#include <hip/hip_runtime.h>
#include <math.h>

#define EMB 1024
#define NB 4
#define SQ 2048
#define TOK (NB*SQ)   // 8192

typedef __attribute__((ext_vector_type(8))) short bhalf8;   // 8 bf16 (4 VGPRs)
typedef __attribute__((ext_vector_type(4))) float f32x4;

__device__ __forceinline__ unsigned short f32_to_bf16(float f) {
    unsigned int u = __float_as_uint(f);
    u += 0x7FFFu + ((u >> 16) & 1u);       // round-to-nearest-even
    return (unsigned short)(u >> 16);
}
__device__ __forceinline__ float bf16_to_f32(unsigned short h) {
    return __uint_as_float(((unsigned int)h) << 16);
}
__device__ __forceinline__ unsigned short f32_to_f16(float f) {
    union { _Float16 h; unsigned short u; } c; c.h = (_Float16)f; return c.u;
}
__device__ __forceinline__ float f16_to_f32(unsigned short u) {
    union { _Float16 h; unsigned short u; } c; c.u = u; return (float)c.h;
}

// ---------------- fused fp32 -> bf16 conversion: x (8192 blocks) + weights (5120) ----------------
__global__ __launch_bounds__(256) void convert_all_kernel(
    const float* __restrict__ x,  unsigned short* __restrict__ x_bf,
    const float* __restrict__ rot, const float* __restrict__ ent,
    const float* __restrict__ gw, unsigned short* __restrict__ w_bf) {
    const int EE4 = EMB * EMB / 4;
    const float* src;
    unsigned short* dst;
    float scale = 1.0f;
    int j;
    if (blockIdx.x < TOK*EMB/4/256) {
        src = x; dst = x_bf; j = blockIdx.x * 256 + threadIdx.x;
        float4 v = ((const float4*)src)[j];
        ushort4 o = { f32_to_bf16(v.x), f32_to_bf16(v.y), f32_to_bf16(v.z), f32_to_bf16(v.w) };
        ((ushort4*)dst)[j] = o;
        return;
    }
    const int i = (blockIdx.x - TOK*EMB/4/256) * 256 + threadIdx.x;   // over 5*EE4
    j = i; dst = w_bf;
    if (i < 3 * EE4) {
        src = rot;
        if (i < EE4) scale = 0.125f;                // 1/sqrt(64) folded into q-rows
    } else if (i < 4 * EE4) { src = ent; j = i - 3 * EE4; }
    else                    { src = gw;  j = i - 4 * EE4; }
    float4 v = ((const float4*)src)[j];
    ushort4 o;
    o.x = f32_to_bf16(v.x * scale);
    o.y = f32_to_bf16(v.y * scale);
    o.z = f32_to_bf16(v.z * scale);
    o.w = f32_to_bf16(v.w * scale);
    ((ushort4*)dst)[i] = o;
}

// ---------------- async global->LDS 16B staging helper ----------------
__device__ __forceinline__ void async_load16(const unsigned short* gp, unsigned short* lp) {
    __builtin_amdgcn_global_load_lds(
        (const __attribute__((address_space(1))) unsigned int*)gp,
        (__attribute__((address_space(3))) unsigned int*)lp,
        16, 0, 0);
}

// =====================================================================================
// Baseline 128x128 NT GEMM (m97 structure): known-good, ~900 TF class, 3-4 blocks/CU.
// Used for the small-grid GEMMs (K4/K5/K6) where the 256^2 tile would leave half the
// machine idle (128 blocks @ 1 block/CU).
// MODE 0: bf16 C; MODE 1: f16 C; MODE 2: Fout = sigmoid(acc) * bf16(Obf)
// =====================================================================================
template <int MODE>
__global__ __launch_bounds__(256) void gemm_nt_128(
    const unsigned short* __restrict__ A,
    const unsigned short* __restrict__ B,
    void* __restrict__ C,
    const unsigned short* __restrict__ Obf,
    float* __restrict__ Fout,
    int M, int N, int K, int lda, int ldb, int ldc,
    long sA, long sB, long sC)
{
    __shared__ __align__(16) unsigned short As[128*64];   // 16 KB
    __shared__ __align__(16) unsigned short Bs[128*64];

    const int bz = blockIdx.z;
    const unsigned short* Ab = A + (long)bz * sA;
    const unsigned short* Bb = B + (long)bz * sB;
    const int bm = blockIdx.x * 128;
    const int bn = blockIdx.y * 128;
    const int t = threadIdx.x;
    const int w = t >> 6;        // wave 0..3
    const int l = t & 63;        // lane
    const int srow8 = l >> 3;
    const int scol  = (((l & 7) ^ ((l >> 3) & 7)) * 8);

    f32x4 zero = {0.f, 0.f, 0.f, 0.f};
    f32x4 acc[4][4];
    #pragma unroll
    for (int i = 0; i < 4; ++i)
        #pragma unroll
        for (int j = 0; j < 4; ++j) acc[i][j] = zero;

    const int wm = (w >> 1) * 64;
    const int wn = (w & 1) * 64;
    const int fr = l & 15;
    const int kqs0 = ((((l >> 4)    ) ^ (l & 7)) * 8);
    const int kqs1 = (((4 + (l >> 4)) ^ (l & 7)) * 8);

    const int nkt = K >> 6;
    for (int kt = 0; kt < nkt; ++kt) {
        const int k0 = kt << 6;
        __syncthreads();
        #pragma unroll
        for (int r = 0; r < 4; ++r) {
            const int rr = (r*4 + w) * 8 + srow8;
            async_load16(Ab + (long)(bm + rr) * lda + (k0 + scol), As + (r*4 + w) * 512);
            async_load16(Bb + (long)(bn + rr) * ldb + (k0 + scol), Bs + (r*4 + w) * 512);
        }
        __syncthreads();

        #pragma unroll
        for (int h = 0; h < 2; ++h) {
            const int kq = h ? kqs1 : kqs0;
            bhalf8 af[4], bfr[4];
            #pragma unroll
            for (int mi = 0; mi < 4; ++mi)
                af[mi] = *(const bhalf8*)(As + (wm + mi*16 + fr) * 64 + kq);
            #pragma unroll
            for (int ni = 0; ni < 4; ++ni)
                bfr[ni] = *(const bhalf8*)(Bs + (wn + ni*16 + fr) * 64 + kq);
            #pragma unroll
            for (int mi = 0; mi < 4; ++mi)
                #pragma unroll
                for (int ni = 0; ni < 4; ++ni)
                    acc[mi][ni] = __builtin_amdgcn_mfma_f32_16x16x32_bf16(
                        af[mi], bfr[ni], acc[mi][ni], 0, 0, 0);
        }
    }

    const int crow = (l >> 4) * 4;
    const int ccol = l & 15;
    #pragma unroll
    for (int mi = 0; mi < 4; ++mi) {
        #pragma unroll
        for (int ni = 0; ni < 4; ++ni) {
            #pragma unroll
            for (int r = 0; r < 4; ++r) {
                const int gr = bm + wm + mi*16 + crow + r;
                const int gc = bn + wn + ni*16 + ccol;
                const float v = acc[mi][ni][r];
                const long idx = (long)gr * ldc + gc;
                if (MODE == 0) {
                    ((unsigned short*)C)[(long)bz*sC + idx] = f32_to_bf16(v);
                } else if (MODE == 1) {
                    ((unsigned short*)C)[(long)bz*sC + idx] = f32_to_f16(v);
                } else {
                    const float o = bf16_to_f32(Obf[idx]);
                    const float g = 1.0f / (1.0f + __expf(-v));
                    Fout[idx] = g * o;
                }
            }
        }
    }
}

// =====================================================================================
// 256x256-tile, BK=64, 8-wave (2Mx4N), phase-interleaved with counted vmcnt.
// ROUND-1 FIX: (a) no sched_barrier(0) / no explicit lgkmcnt -- compiler emits its own
// fine-grained lgkmcnt(N) between ds_read and consuming MFMA (m97-verified behavior);
// (b) barriers cut 8 -> 3 per K-tile, keeping only hazard-required ones:
//   end-P1: all waves' B reads (and A rows of P1) done before B-slot restage (P2/P3)
//   end-P3: A-lo reads of P1-P3 done before P4's A-lo restage
//   end-P4: vmcnt(6) propagation across waves = tile t+1 fully landed
// Barriers are inline-asm s_barrier with "memory" clobber so stage/read issue cannot
// be hoisted across them by the compiler. Own-phase stage-vs-read races (P4) are
// latency-protected: writes arrive >=500cy after issue, reads complete ~120cy (R1
// passed refcheck with the identical pattern).
// Stage stream per tile t: P1 A-hi(t+1)->nxt; P2 B-lo(t+2)->cur; P3 B-hi(t+2)->cur;
// P4 A-lo(t+2)->cur; vmcnt(6) (= t+2's 6 loads outstanding) at end-P4.
// =====================================================================================

#define BARF() asm volatile("s_barrier" ::: "memory")
#define VMC6() asm volatile("s_waitcnt vmcnt(6)" ::: "memory")
#define VMC0() asm volatile("s_waitcnt vmcnt(0)" ::: "memory")

#define STAGE_A(buf, half, kofs) do { \
    async_load16(aG0 + (half)*aH + (kofs), &As[buf][(half)*8192 +        w*512]); \
    async_load16(aG1 + (half)*aH + (kofs), &As[buf][(half)*8192 + 4096 + w*512]); \
} while (0)
#define STAGE_B(buf, half, kofs) do { \
    async_load16(bG0 + (half)*bH + (kofs), &Bs[buf][(half)*8192 +        w*512]); \
    async_load16(bG1 + (half)*bH + (kofs), &Bs[buf][(half)*8192 + 4096 + w*512]); \
} while (0)

#define READ_A(p) do { \
    af[0][0] = *(const bhalf8*)(aRd + ((p)*2    )*1024 + kqs0); \
    af[0][1] = *(const bhalf8*)(aRd + ((p)*2    )*1024 + kqs1); \
    af[1][0] = *(const bhalf8*)(aRd + ((p)*2 + 1)*1024 + kqs0); \
    af[1][1] = *(const bhalf8*)(aRd + ((p)*2 + 1)*1024 + kqs1); \
} while (0)

#define READ_B() do { \
    _Pragma("unroll") \
    for (int ni_ = 0; ni_ < 4; ++ni_) { \
        bfv[ni_][0] = *(const bhalf8*)(bRd + ni_*1024 + kqs0); \
        bfv[ni_][1] = *(const bhalf8*)(bRd + ni_*1024 + kqs1); \
    } \
} while (0)

#define MFMA16(p) do { \
    __builtin_amdgcn_s_setprio(1); \
    _Pragma("unroll") \
    for (int h_ = 0; h_ < 2; ++h_) { \
        _Pragma("unroll") \
        for (int mi_ = 0; mi_ < 2; ++mi_) { \
            _Pragma("unroll") \
            for (int ni_ = 0; ni_ < 4; ++ni_) \
                acc[(p)*2 + mi_][ni_] = __builtin_amdgcn_mfma_f32_16x16x32_bf16( \
                    af[mi_][h_], bfv[ni_][h_], acc[(p)*2 + mi_][ni_], 0, 0, 0); \
        } \
    } \
    __builtin_amdgcn_s_setprio(0); \
} while (0)

template <int MODE>
__global__ __launch_bounds__(512, 2) void gemm_nt_8p(
    const unsigned short* __restrict__ A,
    const unsigned short* __restrict__ B,
    void* __restrict__ C,
    const unsigned short* __restrict__ Obf,
    float* __restrict__ Fout,
    int M, int N, int K, int lda, int ldb, int ldc,
    long sA, long sB, long sC)
{
    __shared__ __align__(16) unsigned short As[2][16384];   // 64 KB  [buf][256*64]
    __shared__ __align__(16) unsigned short Bs[2][16384];   // 64 KB

    const int bz = blockIdx.z;
    const unsigned short* Ab = A + (long)bz * sA;
    const unsigned short* Bb = B + (long)bz * sB;
    const int bm = blockIdx.x * 256;
    const int bn = blockIdx.y * 256;
    const int t = threadIdx.x;
    const int w = t >> 6;        // wave 0..7
    const int l = t & 63;        // lane

    const int srow = l >> 3;
    const int scol = (((l & 7) ^ (l >> 3)) * 8);

    const int fr = l & 15;
    const int kqs0 = ((((l >> 4)    ) ^ (l & 7)) * 8);
    const int kqs1 = (((4 + (l >> 4)) ^ (l & 7)) * 8);

    const int wm = (w >> 2) * 128;   // WARPS_M = 2
    const int wn = (w & 3) * 64;     // WARPS_N = 4

    f32x4 acc[8][4];
    f32x4 zero = {0.f, 0.f, 0.f, 0.f};
    #pragma unroll
    for (int i = 0; i < 8; ++i)
        #pragma unroll
        for (int j = 0; j < 4; ++j) acc[i][j] = zero;

    const unsigned short* aG0 = Ab + (long)(bm + (    w)*8 + srow) * lda + scol;
    const unsigned short* aG1 = Ab + (long)(bm + (8 + w)*8 + srow) * lda + scol;
    const unsigned short* bG0 = Bb + (long)(bn + (    w)*8 + srow) * ldb + scol;
    const unsigned short* bG1 = Bb + (long)(bn + (8 + w)*8 + srow) * ldb + scol;
    const long aH = (long)128 * lda;
    const long bH = (long)128 * ldb;

    const int nkt = K >> 6;            // >= 2 required (16 or 32 here)

    // ---- prologue: tile0 complete (8 loads) + tile1 {B-lo, B-hi, A-lo} (6 loads) ----
    STAGE_A(0, 0, 0);  STAGE_A(0, 1, 0);
    STAGE_B(0, 0, 0);  STAGE_B(0, 1, 0);
    STAGE_B(1, 0, 64); STAGE_B(1, 1, 64);
    STAGE_A(1, 0, 64);
    VMC6();                            // tile0's 8 loads landed; tile1's 6 in flight
    BARF();

    for (int kt = 0; kt < nkt; ++kt) {
        const int cur = kt & 1, nxt = cur ^ 1;
        const unsigned short* aRd = &As[cur][(wm + fr) * 64];
        const unsigned short* bRd = &Bs[cur][(wn + fr) * 64];
        const bool s1 = (kt + 1 < nkt);
        const bool s2 = (kt + 2 < nkt);
        const int k1 = (kt + 1) << 6;
        const int k2 = (kt + 2) << 6;

        bhalf8 bfv[4][2], af[2][2];

        // ---- P1: stage A-hi(t+1) -> other buffer; all B frags + A m0-1; MFMA ----
        if (s1) STAGE_A(nxt, 1, k1);
        READ_B();
        READ_A(0);
        MFMA16(0);
        BARF();                         // B reads + P1 A reads done across waves

        // ---- P2: stage B-lo(t+2) (slots freed at end-P1); A m2-3; MFMA ----
        if (s2) STAGE_B(cur, 0, k2);
        READ_A(1);
        MFMA16(1);
        // (no barrier: P3's stage also only conflicts with P1 reads)

        // ---- P3: stage B-hi(t+2); A m4-5; MFMA ----
        if (s2) STAGE_B(cur, 1, k2);
        READ_A(2);
        MFMA16(2);
        BARF();                         // A-lo reads (P1-P3) done before P4 restage

        // ---- P4: stage A-lo(t+2); A m6-7; MFMA; counted vmcnt once per tile ----
        if (s2) STAGE_A(cur, 0, k2);
        READ_A(3);
        MFMA16(3);
        if (s2) VMC6(); else VMC0();
        BARF();                         // all waves: tile t+1 fully landed
    }

    // C/D layout (m89-verified): col = lane&15, row = (lane>>4)*4 + reg
    const int crow = (l >> 4) * 4;
    const int ccol = l & 15;
    #pragma unroll
    for (int mi = 0; mi < 8; ++mi) {
        #pragma unroll
        for (int ni = 0; ni < 4; ++ni) {
            #pragma unroll
            for (int r = 0; r < 4; ++r) {
                const int gr = bm + wm + mi*16 + crow + r;
                const int gc = bn + wn + ni*16 + ccol;
                const float v = acc[mi][ni][r];
                const long idx = (long)gr * ldc + gc;
                if (MODE == 0) {
                    ((unsigned short*)C)[(long)bz*sC + idx] = f32_to_bf16(v);
                } else if (MODE == 1) {
                    ((unsigned short*)C)[(long)bz*sC + idx] = f32_to_f16(v);
                } else {
                    const float o = bf16_to_f32(Obf[idx]);
                    const float g = 1.0f / (1.0f + __expf(-v));
                    Fout[idx] = g * o;
                }
            }
        }
    }
}

#undef BARF
#undef VMC6
#undef VMC0
#undef STAGE_A
#undef STAGE_B
#undef READ_A
#undef READ_B
#undef MFMA16

// ---------------- row softmax: f16 scores in, bf16 attn out (row len 2048) ----------------
__global__ __launch_bounds__(256) void softmax_kernel(const unsigned short* __restrict__ sc,
                                                      unsigned short* __restrict__ attn) {
    const long row = blockIdx.x;
    const unsigned short* p = sc + row * SQ;
    unsigned short* q = attn + row * SQ;
    const int t = threadIdx.x;
    const int w = t >> 6, l = t & 63;
    union { bhalf8 v; unsigned short u[8]; } in;
    in.v = ((const bhalf8*)p)[t];
    float f[8];
    float m = -1e30f;
    #pragma unroll
    for (int j = 0; j < 8; ++j) { f[j] = f16_to_f32(in.u[j]); m = fmaxf(m, f[j]); }
    #pragma unroll
    for (int off = 32; off; off >>= 1) m = fmaxf(m, __shfl_xor(m, off));
    __shared__ float smax[4], ssum[4];
    if (l == 0) smax[w] = m;
    __syncthreads();
    m = fmaxf(fmaxf(smax[0], smax[1]), fmaxf(smax[2], smax[3]));
    float s = 0.f;
    #pragma unroll
    for (int j = 0; j < 8; ++j) { f[j] = __expf(f[j] - m); s += f[j]; }
    #pragma unroll
    for (int off = 32; off; off >>= 1) s += __shfl_xor(s, off);
    if (l == 0) ssum[w] = s;
    __syncthreads();
    const float inv = 1.0f / (ssum[0] + ssum[1] + ssum[2] + ssum[3]);
    union { bhalf8 v; unsigned short u[8]; } o;
    #pragma unroll
    for (int j = 0; j < 8; ++j) o.u[j] = f32_to_bf16(f[j] * inv);
    ((bhalf8*)q)[t] = o.v;
}

// ---------------- transpose v (per batch: (2048 x 1024, ld 3072) -> (1024 x 2048)) ----------------
__global__ void transpose_v(const unsigned short* __restrict__ qkv,
                            unsigned short* __restrict__ vT) {
    __shared__ unsigned short tile[32][33];
    const int b = blockIdx.z;
    const unsigned short* v = qkv + (long)b * SQ * (3*EMB) + 2*EMB;
    const int e = blockIdx.x * 32 + threadIdx.x;
    const int s = blockIdx.y * 32 + threadIdx.y;
    tile[threadIdx.y][threadIdx.x] = v[(long)s * (3*EMB) + e];
    __syncthreads();
    const int so = blockIdx.y * 32 + threadIdx.x;
    const int eo = blockIdx.x * 32 + threadIdx.y;
    vT[(long)b * EMB * SQ + (long)eo * SQ + so] = tile[threadIdx.x][threadIdx.y];
}

extern "C" void kernel_launch(void* const* d_in, const int* in_sizes, int n_in,
                              void* d_out, int out_size, void* d_ws, size_t ws_size,
                              hipStream_t stream) {
    const float* rot = (const float*)d_in[0];   // (3E, E) row-major
    const float* ent = (const float*)d_in[1];   // (E, E)
    const float* x   = (const float*)d_in[2];   // (B, S, E)
    const float* gw  = (const float*)d_in[3];   // (E, E)
    float* outp = (float*)d_out;
    char* ws = (char*)d_ws;

    size_t off = 0;
    unsigned short* x_bf    = (unsigned short*)(ws + off); off += (size_t)TOK*EMB*2;     // 16 MB
    unsigned short* wqkv_bf = (unsigned short*)(ws + off); off += (size_t)3*EMB*EMB*2;   // 6 MB
    unsigned short* wout_bf = (unsigned short*)(ws + off); off += (size_t)EMB*EMB*2;     // 2 MB
    unsigned short* gate_bf = (unsigned short*)(ws + off); off += (size_t)EMB*EMB*2;     // 2 MB
    unsigned short* qkv_bf  = (unsigned short*)(ws + off); off += (size_t)TOK*3*EMB*2;   // 48 MB
    unsigned short* vT_bf   = (unsigned short*)(ws + off); off += (size_t)NB*EMB*SQ*2;   // 16 MB
    unsigned short* sc_f16  = (unsigned short*)(ws + off); off += (size_t)NB*SQ*SQ*2;    // 32 MB
    // Aliases (lifetimes disjoint, all launches sequential on one stream):
    unsigned short* attn_bf = qkv_bf;                        // qkv dead after K2; attn live K3->K4
    unsigned short* ao_bf   = x_bf;                          // x dead after K1; ao live K4->K5
    unsigned short* out_bf  = qkv_bf + (size_t)NB*SQ*SQ;     // qkv[32MB:48MB], live K5->K6

    // K0: all converts in one launch
    convert_all_kernel<<<dim3(TOK*EMB/4/256 + 5*EMB*EMB/4/256), dim3(256), 0, stream>>>(
        x, x_bf, rot, ent, gw, wqkv_bf);

    // K1: qkv = x @ w_qkv^T   (8192 x 3072, K=1024) -> bf16   [384 blocks, 8-phase 256^2]
    gemm_nt_8p<0><<<dim3(TOK/256, 3*EMB/256, 1), dim3(512), 0, stream>>>(
        x_bf, wqkv_bf, qkv_bf, nullptr, nullptr,
        TOK, 3*EMB, EMB, EMB, EMB, 3*EMB, 0, 0, 0);

    // transpose v -> vT (per batch E x S)
    transpose_v<<<dim3(EMB/32, SQ/32, NB), dim3(32, 32), 0, stream>>>(qkv_bf, vT_bf);

    // K2: scores = q @ k^T per batch (2048 x 2048, K=1024) -> f16  [256 blocks exact, 8-phase]
    gemm_nt_8p<1><<<dim3(SQ/256, SQ/256, NB), dim3(512), 0, stream>>>(
        qkv_bf, qkv_bf + EMB, sc_f16, nullptr, nullptr,
        SQ, SQ, EMB, 3*EMB, 3*EMB, SQ,
        (long)SQ*3*EMB, (long)SQ*3*EMB, (long)SQ*SQ);

    // K3: softmax rows (f16 in, bf16 out)
    softmax_kernel<<<dim3(NB*SQ), dim3(256), 0, stream>>>(sc_f16, attn_bf);

    // K4: attn_out = attn @ v per batch (2048 x 1024, K=2048)  [512 blocks, 128^2 kernel]
    gemm_nt_128<0><<<dim3(SQ/128, EMB/128, NB), dim3(256), 0, stream>>>(
        attn_bf, vT_bf, ao_bf, nullptr, nullptr,
        SQ, EMB, SQ, SQ, SQ, EMB,
        (long)SQ*SQ, (long)EMB*SQ, (long)SQ*EMB);

    // K5: out = attn_out @ w_out^T (8192 x 1024, K=1024) -> bf16  [512 blocks, 128^2]
    gemm_nt_128<0><<<dim3(TOK/128, EMB/128, 1), dim3(256), 0, stream>>>(
        ao_bf, wout_bf, out_bf, nullptr, nullptr,
        TOK, EMB, EMB, EMB, EMB, EMB, 0, 0, 0);

    // K6: result = sigmoid(out @ gate_w^T) * out_bf -> fp32 d_out  [512 blocks, 128^2]
    gemm_nt_128<2><<<dim3(TOK/128, EMB/128, 1), dim3(256), 0, stream>>>(
        out_bf, gate_bf, nullptr, out_bf, outp,
        TOK, EMB, EMB, EMB, EMB, EMB, 0, 0, 0);
}